// Round 6
// baseline (9732.291 us; speedup 1.0000x reference)
//
#include <hip/hip_runtime.h>
#include <hip/hip_bf16.h>
#include <math.h>

// Problem constants
#define BB 128
#define TT 1024
#define DD 256
#define HH 256
#define MM (BB * TT)
#define NN3 768

#define NCONS 16         // consumer blocks: 8 batch-groups x 2 column-halves
#define NPROD 240        // producers: 6 n-slices x 40 batch-groups
#define WIN_TILES 768
#define XW_BYTES ((size_t)MM * NN3 * 2)   // 192 MiB

typedef __attribute__((ext_vector_type(8))) short short8;
typedef __attribute__((ext_vector_type(4))) float f32x4;
typedef unsigned long long ull;
typedef __attribute__((address_space(1))) unsigned int gu32;
typedef __attribute__((address_space(3))) unsigned int lu32;

static __device__ __forceinline__ float bf2f(unsigned int u16) {
    return __uint_as_float(u16 << 16);
}
static __device__ __forceinline__ unsigned short f2bf(float f) {   // RNE
    unsigned int u = __float_as_uint(f);
    unsigned int r = u + 0x7FFFu + ((u >> 16) & 1u);
    return (unsigned short)(r >> 16);
}
static __device__ __forceinline__ unsigned short f2bf_fast(float f) {
    return (unsigned short)((__float_as_uint(f) + 0x8000u) >> 16);
}
static __device__ __forceinline__ void barrier_full() {
    asm volatile("s_waitcnt vmcnt(0) lgkmcnt(0)\n\ts_barrier" ::: "memory");
}

// ---------------------------------------------------------------------------
// Fused kernel.
// Blocks 0..15: GRU consumers. bid = half*8 + g: batch-group g (16 batches),
//   column half (128 cols of each gate). Pair = bid ^ 8.
// Blocks 16..255: xproj producers (unchanged from R5), window-signalled.
// ---------------------------------------------------------------------------
__global__ __launch_bounds__(512)
__attribute__((amdgpu_waves_per_eu(2, 2)))
void gru_fused_kernel(
    const float* __restrict__ x,
    const float* __restrict__ Wz, const float* __restrict__ Wr,
    const float* __restrict__ Wh,
    const float* __restrict__ Uz, const float* __restrict__ Ur,
    const float* __restrict__ Uh,
    const float* __restrict__ bz, const float* __restrict__ br,
    const float* __restrict__ bh,
    unsigned short* __restrict__ xw,
    char* __restrict__ ctrl,
    float* __restrict__ out)
{
    // LDS (allocated for all blocks; pad forces low occupancy => 1 block/CU)
    __shared__ unsigned short xstage[2][6144];   // 2 x 12 KiB (own 3 gate-runs)
    __shared__ short hA[16][136];                // own-half h, A-layout
    __shared__ short rhA[16][136];               // own-half r*h, A-layout
    __shared__ ull lds_pad[4096];                // 32 KiB occupancy pad

    const int tid  = threadIdx.x;
    const int lane = tid & 63;
    const int wv   = tid >> 6;
    const int nq   = lane & 15;
    const int kq   = lane >> 4;

    if ((size_t)out == 1) ((volatile ull*)lds_pad)[0] = 1;  // keep pad alive

    unsigned int* cnt = (unsigned int*)ctrl;                 // [8]
    unsigned int* hfl = (unsigned int*)(ctrl + 1024);        // slot*64 dwords
    unsigned int* rfl = (unsigned int*)(ctrl + 8192);
    ull* hbufs = (ull*)(ctrl + 16384);                       // (slot*2+par)*512
    ull* rbufs = (ull*)(ctrl + 16384 + 131072);

    if (blockIdx.x >= NCONS) {
        // ================= producer (R5 structure) =================
        const int p   = blockIdx.x - NCONS;
        const int nb  = p % 6;
        const int bg  = p / 6;
        const int n0  = nb * 128;
        const int g   = n0 >> 8;
        const int nc0 = n0 & 255;
        const float* W    = (g == 0) ? Wz : (g == 1 ? Wr : Wh);
        const float* bias = (g == 0) ? bz : (g == 1 ? br : bh);
        const int nh = wv >> 2;
        const int mq = wv & 3;

        short8 wf[8][4];
#pragma unroll
        for (int c = 0; c < 8; ++c)
#pragma unroll
            for (int nt = 0; nt < 4; ++nt) {
                short8 f;
                const int col = nc0 + nh * 64 + nt * 16 + nq;
#pragma unroll
                for (int j = 0; j < 8; ++j)
                    f[j] = (short)f2bf(W[(size_t)(c * 32 + kq * 8 + j) * HH + col]);
                wf[c][nt] = f;
            }
        float bv[4];
#pragma unroll
        for (int nt = 0; nt < 4; ++nt)
            bv[nt] = bias[nc0 + nh * 64 + nt * 16 + nq];

        for (int w = 0; w < 8; ++w) {
            for (int b = bg; b < BB; b += 40) {
                const int m0 = (b * 8 + w) * 128;
                f32x4 acc[2][4];
#pragma unroll
                for (int mi = 0; mi < 2; ++mi)
#pragma unroll
                    for (int nt = 0; nt < 4; ++nt)
                        acc[mi][nt] = (f32x4){0.f, 0.f, 0.f, 0.f};

#pragma unroll
                for (int c = 0; c < 8; ++c) {
                    short8 af[2];
#pragma unroll
                    for (int mi = 0; mi < 2; ++mi) {
                        const float* xp = &x[(size_t)(m0 + mq * 32 + mi * 16 + nq) * DD
                                             + c * 32 + kq * 8];
                        float4 f0 = *(const float4*)xp;
                        float4 f1 = *(const float4*)(xp + 4);
                        short8 a;
                        a[0] = (short)f2bf_fast(f0.x); a[1] = (short)f2bf_fast(f0.y);
                        a[2] = (short)f2bf_fast(f0.z); a[3] = (short)f2bf_fast(f0.w);
                        a[4] = (short)f2bf_fast(f1.x); a[5] = (short)f2bf_fast(f1.y);
                        a[6] = (short)f2bf_fast(f1.z); a[7] = (short)f2bf_fast(f1.w);
                        af[mi] = a;
                    }
#pragma unroll
                    for (int mi = 0; mi < 2; ++mi)
#pragma unroll
                        for (int nt = 0; nt < 4; ++nt)
                            acc[mi][nt] = __builtin_amdgcn_mfma_f32_16x16x32_bf16(
                                af[mi], wf[c][nt], acc[mi][nt], 0, 0, 0);
                }

                const int tb   = (m0 & 1023) + mq * 32;
                const int bb   = m0 >> 10;
                const int bid2 = bb >> 4, brow = bb & 15;
                const int lane4 = (brow >> 2) * 16 + nq;
                const int ii    = brow & 3;
#pragma unroll
                for (int mi = 0; mi < 2; ++mi)
#pragma unroll
                    for (int nt = 0; nt < 4; ++nt) {
                        int ti = g * 16 + (nc0 >> 4) + nh * 4 + nt;
#pragma unroll
                        for (int i = 0; i < 4; ++i) {
                            int t = tb + mi * 16 + kq * 4 + i;
                            xw[(size_t)(t * 8 + bid2) * 12288
                               + (size_t)(ti * 256 + lane4 * 4 + ii)] =
                                f2bf(acc[mi][nt][i] + bv[nt]);
                        }
                    }

                __syncthreads();
                if (tid == 0) {
                    __threadfence();
                    __hip_atomic_fetch_add(&cnt[w], 1u, __ATOMIC_RELEASE,
                                           __HIP_MEMORY_SCOPE_AGENT);
                }
            }
        }
        return;
    }

    // ================= consumer =================
    const int bid  = blockIdx.x;
    const int g7   = bid & 7;        // batch-group
    const int half = bid >> 3;       // column half
    const int slot = bid, pslot = bid ^ 8;

    ull* hmine[2] = { hbufs + (slot * 2 + 0) * 512, hbufs + (slot * 2 + 1) * 512 };
    ull* hpart[2] = { hbufs + (pslot * 2 + 0) * 512, hbufs + (pslot * 2 + 1) * 512 };
    ull* rmine[2] = { rbufs + (slot * 2 + 0) * 512, rbufs + (slot * 2 + 1) * 512 };
    ull* rpart[2] = { rbufs + (pslot * 2 + 0) * 512, rbufs + (pslot * 2 + 1) * 512 };
    unsigned int* hf_me = hfl + slot * 64;
    unsigned int* hf_pa = hfl + pslot * 64;
    unsigned int* rf_me = rfl + slot * 64;
    unsigned int* rf_pa = rfl + pslot * 64;

    // ---- persistent weights: wave owns 16-col tile (half*128 + wv*16) of all
    // three gates. 3 x 8 chunks x 4 regs = 96 regs. ----
    const int ct0 = half * 128 + wv * 16 + nq;
    short8 wz[8], wr8[8], wh8[8];
#pragma unroll
    for (int c = 0; c < 8; ++c) {
        short8 a, b, d;
#pragma unroll
        for (int j = 0; j < 8; ++j) {
            size_t row = (size_t)(c * 32 + kq * 8 + j) * HH;
            a[j] = (short)f2bf(Uz[row + ct0]);
            b[j] = (short)f2bf(Ur[row + ct0]);
            d[j] = (short)f2bf(Uh[row + ct0]);
        }
        wz[c] = a; wr8[c] = b; wh8[c] = d;
    }

    // ---- init ----
    for (int idx = tid; idx < 16 * 136; idx += 512) ((short*)hA)[idx] = 0;
    float hprev[4];
#pragma unroll
    for (int i = 0; i < 4; ++i) hprev[i] = 0.f;
    __hip_atomic_store(hmine[0] + tid, 0ull, __ATOMIC_RELAXED,
                       __HIP_MEMORY_SCOPE_AGENT);   // zero h buf parity 0

    auto stage = [&](int t, int buf) {
        const char* gsrc = (const char*)(xw + (size_t)(t * 8 + g7) * 12288);
        char* lb = (char*)&xstage[buf][0];
        for (int ld = wv; ld < 12; ld += 8) {
            int r = ld >> 2, s = ld & 3;
            int goff = (r * 16 + half * 8) * 512 + s * 1024;
            int loff = r * 4096 + s * 1024;
            __builtin_amdgcn_global_load_lds((const gu32*)(gsrc + goff + lane * 16),
                                             (lu32*)(lb + loff), 16, 0, 0);
        }
    };

    // 16x16 C-layout -> A-layout in-wave transpose; returns 4 shorts (row r =
    // lane&15, cols 4*(lane>>4)..+3) packed in a ull.
    auto transpose_tile = [&](unsigned int d0, unsigned int d1) -> ull {
        const int r = lane & 15, gq = lane >> 4;
        const int base = (((r >> 2) << 4) | (gq << 2)) << 2;   // byte addr
        unsigned int o[4];
#pragma unroll
        for (int j = 0; j < 4; ++j) {
            int t0 = __builtin_amdgcn_ds_bpermute(base + (j << 2), (int)d0);
            int t1 = __builtin_amdgcn_ds_bpermute(base + (j << 2), (int)d1);
            unsigned int w = (r & 2) ? (unsigned int)t1 : (unsigned int)t0;
            o[j] = (w >> ((r & 1) * 16)) & 0xffffu;
        }
        unsigned int lo = o[0] | (o[1] << 16);
        unsigned int hi = o[2] | (o[3] << 16);
        return (ull)lo | ((ull)hi << 32);
    };
    const int tr_r = lane & 15, tr_g = lane >> 4;
    const int lds_tr  = tr_r * 136 + wv * 16 + tr_g * 4;      // shorts
    const int buf_tr  = tr_r * 16 + wv * 2 + (tr_g >> 1);     // hmm see below

    // global exchange buffer index for transposed store:
    // buffer [row 16][col-local 128] shorts; ull idx = (row*128 + wv*16 + 4g)/4? 
    // bytes = row*256 + (wv*16+4g)*2 -> /8 = row*32 + wv*4 + g
    const int buf_idx = tr_r * 32 + wv * 4 + tr_g;

    auto spin_rel = [&](const unsigned int* f, unsigned int v) {
        while (__hip_atomic_load(f, __ATOMIC_RELAXED,
                                 __HIP_MEMORY_SCOPE_AGENT) < v) {}
    };
    auto spin_acq = [&](const unsigned int* f, unsigned int v) {
        while (__hip_atomic_load(f, __ATOMIC_ACQUIRE,
                                 __HIP_MEMORY_SCOPE_AGENT) < v) {}
    };

    int done_w = 1;
    spin_acq(&cnt[0], WIN_TILES);
    stage(0, 0);
    barrier_full();                       // zeros ack'd + stage 0 landed
    if (tid == 0)
        __hip_atomic_store(hf_me, 1u, __ATOMIC_RELAXED, __HIP_MEMORY_SCOPE_AGENT);

    for (int t = 0; t < TT; ++t) {
        const int par = t & 1;
        const unsigned short* xs = &xstage[par][0];

        // partner h ready?
        spin_rel(hf_pa, (unsigned int)(t + 1));

        // partner-half A-fragments of h (4 chunks x 16B), straight from MALL
        short8 afh[4];
#pragma unroll
        for (int c2 = 0; c2 < 4; ++c2) {
            size_t off = (size_t)nq * 32 + c2 * 8 + kq * 2;   // ull units
            union { ull u[2]; short8 s; } cv;
            cv.u[0] = __hip_atomic_load(hpart[par] + off, __ATOMIC_RELAXED,
                                        __HIP_MEMORY_SCOPE_AGENT);
            cv.u[1] = __hip_atomic_load(hpart[par] + off + 1, __ATOMIC_RELAXED,
                                        __HIP_MEMORY_SCOPE_AGENT);
            afh[c2] = cv.s;
        }

        // ---- phase A ----
        f32x4 a0, a1;
        {
            uint2 uz = *(const uint2*)&xs[0 * 2048 + wv * 256 + lane * 4];
            uint2 ur = *(const uint2*)&xs[1 * 2048 + wv * 256 + lane * 4];
            a0[0] = bf2f(uz.x & 0xffffu); a0[1] = bf2f(uz.x >> 16);
            a0[2] = bf2f(uz.y & 0xffffu); a0[3] = bf2f(uz.y >> 16);
            a1[0] = bf2f(ur.x & 0xffffu); a1[1] = bf2f(ur.x >> 16);
            a1[2] = bf2f(ur.y & 0xffffu); a1[3] = bf2f(ur.y >> 16);
        }
#pragma unroll
        for (int c2 = 0; c2 < 4; ++c2) {       // own chunks from LDS
            short8 af = *(const short8*)&hA[nq][c2 * 32 + kq * 8];
            int c = 4 * half + c2;
            a0 = __builtin_amdgcn_mfma_f32_16x16x32_bf16(af, wz[c], a0, 0, 0, 0);
            a1 = __builtin_amdgcn_mfma_f32_16x16x32_bf16(af, wr8[c], a1, 0, 0, 0);
        }
#pragma unroll
        for (int c2 = 0; c2 < 4; ++c2) {       // partner chunks from MALL
            int c = 4 * (1 - half) + c2;
            a0 = __builtin_amdgcn_mfma_f32_16x16x32_bf16(afh[c2], wz[c], a0, 0, 0, 0);
            a1 = __builtin_amdgcn_mfma_f32_16x16x32_bf16(afh[c2], wr8[c], a1, 0, 0, 0);
        }

        // r-epilogue: rh (bf16) -> transpose -> LDS own + MALL partner copy
        {
            unsigned int v01, v23;
            {
                float r0 = __builtin_amdgcn_fmed3f(__builtin_fmaf(0.2f, a1[0], 0.5f), 0.f, 1.f);
                float r1 = __builtin_amdgcn_fmed3f(__builtin_fmaf(0.2f, a1[1], 0.5f), 0.f, 1.f);
                float r2 = __builtin_amdgcn_fmed3f(__builtin_fmaf(0.2f, a1[2], 0.5f), 0.f, 1.f);
                float r3 = __builtin_amdgcn_fmed3f(__builtin_fmaf(0.2f, a1[3], 0.5f), 0.f, 1.f);
                v01 = (unsigned int)f2bf_fast(r0 * hprev[0])
                    | ((unsigned int)f2bf_fast(r1 * hprev[1]) << 16);
                v23 = (unsigned int)f2bf_fast(r2 * hprev[2])
                    | ((unsigned int)f2bf_fast(r3 * hprev[3]) << 16);
            }
            ull tv = transpose_tile(v01, v23);
            *(ull*)&((short*)rhA)[lds_tr] = tv;
            __hip_atomic_store(rmine[par] + buf_idx, tv, __ATOMIC_RELAXED,
                               __HIP_MEMORY_SCOPE_AGENT);
        }
        barrier_full();                        // rh stores ack'd, LDS visible
        if (tid == 0)
            __hip_atomic_store(rf_me, (unsigned int)(t + 1), __ATOMIC_RELAXED,
                               __HIP_MEMORY_SCOPE_AGENT);

        // window gate + next-step stage (into other buffer)
        int tn2 = (t + 1 < TT) ? (t + 1) : (TT - 1);
        int w2 = tn2 >> 7;
        if (w2 >= done_w) { spin_acq(&cnt[w2], WIN_TILES); done_w = w2 + 1; }
        stage(tn2, par ^ 1);

        spin_rel(rf_pa, (unsigned int)(t + 1));

        short8 afr[4];
#pragma unroll
        for (int c2 = 0; c2 < 4; ++c2) {
            size_t off = (size_t)nq * 32 + c2 * 8 + kq * 2;
            union { ull u[2]; short8 s; } cv;
            cv.u[0] = __hip_atomic_load(rpart[par] + off, __ATOMIC_RELAXED,
                                        __HIP_MEMORY_SCOPE_AGENT);
            cv.u[1] = __hip_atomic_load(rpart[par] + off + 1, __ATOMIC_RELAXED,
                                        __HIP_MEMORY_SCOPE_AGENT);
            afr[c2] = cv.s;
        }

        // ---- phase B ----
        f32x4 ah;
        {
            uint2 uh = *(const uint2*)&xs[2 * 2048 + wv * 256 + lane * 4];
            ah[0] = bf2f(uh.x & 0xffffu); ah[1] = bf2f(uh.x >> 16);
            ah[2] = bf2f(uh.y & 0xffffu); ah[3] = bf2f(uh.y >> 16);
        }
#pragma unroll
        for (int c2 = 0; c2 < 4; ++c2) {
            short8 af = *(const short8*)&rhA[nq][c2 * 32 + kq * 8];
            ah = __builtin_amdgcn_mfma_f32_16x16x32_bf16(af, wh8[4 * half + c2], ah, 0, 0, 0);
        }
#pragma unroll
        for (int c2 = 0; c2 < 4; ++c2)
            ah = __builtin_amdgcn_mfma_f32_16x16x32_bf16(
                afr[c2], wh8[4 * (1 - half) + c2], ah, 0, 0, 0);

        // h-epilogue
        {
            unsigned int v01, v23;
            unsigned short us[4];
#pragma unroll
            for (int i = 0; i < 4; ++i) {
                float z = __builtin_amdgcn_fmed3f(
                    __builtin_fmaf(0.2f, a0[i], 0.5f), 0.f, 1.f);
                float a = __builtin_amdgcn_fmed3f(ah[i], -12.f, 12.f);
                float a2 = a * 2.88539008f;
                float e;
                asm("v_exp_f32 %0, %1" : "=v"(e) : "v"(a2));
                float hh = __builtin_fmaf(-2.f, __builtin_amdgcn_rcpf(e + 1.f), 1.f);
                float hn = __builtin_fmaf(z, hprev[i] - hh, hh);
                hprev[i] = hn;
                us[i] = f2bf_fast(hn);
            }
            v01 = (unsigned int)us[0] | ((unsigned int)us[1] << 16);
            v23 = (unsigned int)us[2] | ((unsigned int)us[3] << 16);
            ull tv = transpose_tile(v01, v23);
            *(ull*)&((short*)hA)[lds_tr] = tv;
            __hip_atomic_store(hmine[par ^ 1] + buf_idx, tv, __ATOMIC_RELAXED,
                               __HIP_MEMORY_SCOPE_AGENT);
        }
        barrier_full();                        // h stores ack'd + stage drained
        if (tid == 0)
            __hip_atomic_store(hf_me, (unsigned int)(t + 2), __ATOMIC_RELAXED,
                               __HIP_MEMORY_SCOPE_AGENT);
    }

#pragma unroll
    for (int i = 0; i < 4; ++i)
        out[(size_t)(g7 * 16 + kq * 4 + i) * HH + ct0] = hprev[i];
}

// ---------------------------------------------------------------------------
extern "C" void kernel_launch(void* const* d_in, const int* in_sizes, int n_in,
                              void* d_out, int out_size, void* d_ws, size_t ws_size,
                              hipStream_t stream) {
    const float* x  = (const float*)d_in[0];
    const float* Wz = (const float*)d_in[1];
    const float* Wr = (const float*)d_in[2];
    const float* Wh = (const float*)d_in[3];
    const float* Uz = (const float*)d_in[4];
    const float* Ur = (const float*)d_in[5];
    const float* Uh = (const float*)d_in[6];
    const float* bz = (const float*)d_in[7];
    const float* br = (const float*)d_in[8];
    const float* bh = (const float*)d_in[9];
    float* out = (float*)d_out;

    // ws: [xw 192Mi][ctrl: cnt+flags 16K, h bufs 128K, rh bufs 128K]
    unsigned short* xw = (unsigned short*)d_ws;
    char* ctrl = (char*)d_ws + XW_BYTES;

    hipMemsetAsync(ctrl, 0, 16384, stream);   // cnt + flags only

    gru_fused_kernel<<<NCONS + NPROD, 512, 0, stream>>>(
        x, Wz, Wr, Wh, Uz, Ur, Uh, bz, br, bh, xw, ctrl, out);
}